// Round 15
// baseline (6142.469 us; speedup 1.0000x reference)
//
#include <hip/hip_runtime.h>
#include <math.h>

#define TSTEPS 512
#define BATCH  64
#define HDIM   1024
#define IDIM   128
#define NBLOCKS 256   // blocks 0..127: layer 0; 128..255: layer 1 (1 block/CU)
#define NTHR   1024   // 16 waves: (m2 0..1) x (kh 0..7) -> 4 waves/SIMD

typedef __attribute__((ext_vector_type(8))) short bf16x8;
typedef __attribute__((ext_vector_type(4))) float f32x4;
typedef __attribute__((ext_vector_type(4))) unsigned u32x4;

// ---- ws: bf16 hi/lo weight planes (ushort units), then barrier area ----
#define WI0HI 0
#define WI0LO (WI0HI + 1024*128)
#define WH0HI (WI0LO + 1024*128)
#define WH0LO (WH0HI + 1024*1024)
#define WI1HI (WH0LO + 1024*1024)
#define WI1LO (WI1HI + 1024*1024)
#define WH1HI (WI1LO + 1024*1024)
#define WH1LO (WH1HI + 1024*1024)
#define WS_USHORTS (WH1LO + 1024*1024)
#define CNT_OFF_BYTES ((size_t)WS_USHORTS * 2)
// barrier area (dword offsets from cnt):
//   arrivals: 256 lines (L0 = 0..127, L1 = 128..255)
//   flagL0:   256 lines at FLG_DW      (published by block 0)
//   flagL1:   256 lines at FLG_DW+4096 (published by block 128)
#define FLG_DW (256 * 16)
#define BAR_BYTES (3 * 256 * 64)   // 48 KB

__device__ __forceinline__ unsigned short bf_hi(float f) {
    unsigned u = __builtin_bit_cast(unsigned, f);
    unsigned r = u + 0x7fffu + ((u >> 16) & 1u);
    return (unsigned short)(r >> 16);
}
__device__ __forceinline__ float bf_tof(unsigned short h) {
    unsigned u = ((unsigned)h) << 16;
    return __builtin_bit_cast(float, u);
}

// fp32x8 (two f32x4 VALUES) -> bf16 hi + lo fragments via v_cvt_pk_bf16_f32
__device__ __forceinline__ void split8v(f32x4 a, f32x4 b,
                                        bf16x8& ah, bf16x8& al) {
    float fv[8] = {a[0], a[1], a[2], a[3], b[0], b[1], b[2], b[3]};
    u32x4 H, L;
    #pragma unroll
    for (int q = 0; q < 4; ++q) {
        const float f0 = fv[2 * q], f1 = fv[2 * q + 1];
        unsigned h;
        asm("v_cvt_pk_bf16_f32 %0, %1, %2" : "=v"(h) : "v"(f0), "v"(f1));
        const float h0 = __builtin_bit_cast(float, h << 16);
        const float h1 = __builtin_bit_cast(float, h & 0xffff0000u);
        unsigned lo;
        asm("v_cvt_pk_bf16_f32 %0, %1, %2" : "=v"(lo) : "v"(f0 - h0), "v"(f1 - h1));
        H[q] = h; L[q] = lo;
    }
    ah = __builtin_bit_cast(bf16x8, H);
    al = __builtin_bit_cast(bf16x8, L);
}

// one 32-k chunk from PRELOADED values: split + 3 MFMA (round-8..13 numerics)
__device__ __forceinline__ void ks_r2(f32x4 a, f32x4 b,
                                      bf16x8 bh, bf16x8 bl, f32x4& acc) {
    bf16x8 ah, al;
    split8v(a, b, ah, al);
    acc = __builtin_amdgcn_mfma_f32_16x16x32_bf16(ah, bh, acc, 0, 0, 0);
    acc = __builtin_amdgcn_mfma_f32_16x16x32_bf16(al, bh, acc, 0, 0, 0);
    acc = __builtin_amdgcn_mfma_f32_16x16x32_bf16(ah, bl, acc, 0, 0, 0);
}

// load 2 chunks (4 x dwordx4) of group g into a named buffer (static idx)
#define LD2(B, base, g) _Pragma("unroll") for (int c = 0; c < 2; ++c) { \
    (B)[2*c]   = *(const f32x4*)((base) + ((g)*2 + c) * 32); \
    (B)[2*c+1] = *(const f32x4*)((base) + ((g)*2 + c) * 32 + 4); }
// process 2 chunks of group g against weight frags wfh/wfl[g*2 + c]
#define PR2(B, g) _Pragma("unroll") for (int c = 0; c < 2; ++c) { \
    ks_r2((B)[2*c], (B)[2*c+1], wfh[(g)*2+c], wfl[(g)*2+c], \
          ((((g)*2+c) & 1) ? accA : accB)); }

// split fp32 weights into bf16 hi/lo planes in ws ([j][k] row-major)
__global__ void prep_kernel(const float* __restrict__ Wi0, const float* __restrict__ Wh0,
                            const float* __restrict__ Wi1, const float* __restrict__ Wh1,
                            unsigned short* __restrict__ wsU)
{
    const int n = 1024*128 + 3*1024*1024;
    for (int e = blockIdx.x * blockDim.x + threadIdx.x; e < n;
         e += gridDim.x * blockDim.x) {
        const float* src; int idx, hiOff, loOff;
        if (e < 1024*128)            { src = Wi0; idx = e;              hiOff = WI0HI; loOff = WI0LO; }
        else if (e < 1024*128 + 1024*1024)   { src = Wh0; idx = e - 1024*128;   hiOff = WH0HI; loOff = WH0LO; }
        else if (e < 1024*128 + 2*1024*1024) { src = Wi1; idx = e - 1024*128 - 1024*1024; hiOff = WI1HI; loOff = WI1LO; }
        else                         { src = Wh1; idx = e - 1024*128 - 2*1024*1024; hiOff = WH1HI; loOff = WH1LO; }
        float f = src[idx];
        unsigned short h = bf_hi(f);
        wsU[hiOff + idx] = h;
        wsU[loOff + idx] = bf_hi(f - bf_tof(h));
    }
}

// --- Layer-decoupled one-reader-per-line barriers (round-13 proven) ---
__device__ __forceinline__ void barrier_arrive(unsigned* cnt, unsigned epoch) {
    __syncthreads();   // drain all waves' sc1 data stores (vmcnt 0)
    if (threadIdx.x == 0)
        __hip_atomic_store(cnt + (unsigned)blockIdx.x * 16, epoch,
                           __ATOMIC_RELAXED, __HIP_MEMORY_SCOPE_AGENT);
}
__device__ __forceinline__ void barrier_wait(unsigned* cnt, unsigned epoch, int layer) {
    const int tid = (int)threadIdx.x;
    const int bid = (int)blockIdx.x;
    if ((bid & 127) == 0) {
        // this layer's aggregator: sweep 128 arrival lines, publish flags
        if (tid < 64) {
            unsigned* arr = cnt + layer * (128 * 16);
            for (;;) {
                unsigned v0 = __hip_atomic_load(arr + (tid     ) * 16, __ATOMIC_RELAXED, __HIP_MEMORY_SCOPE_AGENT);
                unsigned v1 = __hip_atomic_load(arr + (tid + 64) * 16, __ATOMIC_RELAXED, __HIP_MEMORY_SCOPE_AGENT);
                bool ok = (v0 >= epoch) & (v1 >= epoch);
                if (__ballot(ok) == ~0ull) break;
                __builtin_amdgcn_s_sleep(1);
            }
            unsigned* flg = cnt + FLG_DW + layer * 4096;
            #pragma unroll
            for (int q = 0; q < 4; ++q)
                __hip_atomic_store(flg + (q * 64 + tid) * 16, epoch,
                                   __ATOMIC_RELAXED, __HIP_MEMORY_SCOPE_AGENT);
        }
        // L1 aggregator must also observe L0's epoch (e0[t] ready)
        if (layer == 1 && tid == 0) {
            unsigned* f0 = cnt + FLG_DW + (unsigned)bid * 16;
            while (__hip_atomic_load(f0, __ATOMIC_RELAXED,
                                     __HIP_MEMORY_SCOPE_AGENT) < epoch)
                __builtin_amdgcn_s_sleep(1);
        }
    } else if (tid == 0) {
        unsigned* f0 = cnt + FLG_DW + (unsigned)bid * 16;
        if (layer == 0) {
            while (__hip_atomic_load(f0, __ATOMIC_RELAXED,
                                     __HIP_MEMORY_SCOPE_AGENT) < epoch)
                __builtin_amdgcn_s_sleep(1);
        } else {
            unsigned* f1 = cnt + FLG_DW + 4096 + (unsigned)bid * 16;
            for (;;) {
                unsigned a = __hip_atomic_load(f1, __ATOMIC_RELAXED, __HIP_MEMORY_SCOPE_AGENT);
                unsigned b = __hip_atomic_load(f0, __ATOMIC_RELAXED, __HIP_MEMORY_SCOPE_AGENT);
                if (a >= epoch && b >= epoch) break;
                __builtin_amdgcn_s_sleep(1);
            }
        }
    }
    __syncthreads();
}

// Persistent layer-decoupled kernel, 1024 threads (16 waves = 4 waves/SIMD).
// out[] IS the state trajectory; sc1 write-through stores, normal-cached
// first-touch reads (round-8 proven). Block = 32 batch-rows x 16 j-cols;
// waves = (m2: 16-row half) x (kh: 8-way K split).
__global__ __launch_bounds__(NTHR, 4) void reservoir_kernel(
    const float* __restrict__ x, float* __restrict__ out,
    const unsigned short* __restrict__ wsU, unsigned* __restrict__ cnt)
{
    __shared__ f32x4 red[16 * 64];   // 16 KB

    const int bid = blockIdx.x;
    const int layer = bid >> 7;
    const int rr  = bid & 127;
    const int jt  = rr >> 1, mh = rr & 1;
    const int tid = (int)threadIdx.x;
    const int w   = __builtin_amdgcn_readfirstlane(tid >> 6);   // 0..15
    const int m2  = w & 1, kh = w >> 1;                          // kh 0..7
    const int l   = tid & 63, lr = l & 15, tq = l >> 4;
    const int jbase = jt * 16;
    const int arow  = mh * 32 + m2 * 16 + lr;   // this lane's A row (batch)

    // ---- load this wave's weight fragments into registers (once) ----
    bf16x8 wfh[8], wfl[8];
    bf16x8 wxh = {}, wxl = {};   // layer-0 x-part frag (kh<4 only)
    if (layer == 0) {
        const size_t rh = (size_t)(jbase + lr) * HDIM + kh * 128 + tq * 8;
        #pragma unroll
        for (int c = 0; c < 4; ++c) {
            wfh[c] = *(const bf16x8*)(wsU + WH0HI + rh + c * 32);
            wfl[c] = *(const bf16x8*)(wsU + WH0LO + rh + c * 32);
        }
        if (kh < 4) {
            const size_t rx = (size_t)(jbase + lr) * IDIM + kh * 32 + tq * 8;
            wxh = *(const bf16x8*)(wsU + WI0HI + rx);
            wxl = *(const bf16x8*)(wsU + WI0LO + rx);
        }
    } else {
        const int hiOff = (kh < 4) ? WI1HI : WH1HI;
        const int loOff = (kh < 4) ? WI1LO : WH1LO;
        const size_t ro = (size_t)(jbase + lr) * HDIM + (kh & 3) * 256 + tq * 8;
        #pragma unroll
        for (int c = 0; c < 8; ++c) {
            wfh[c] = *(const bf16x8*)(wsU + hiOff + ro + c * 32);
            wfl[c] = *(const bf16x8*)(wsU + loOff + ro + c * 32);
        }
    }

    // finalize mapping: threads tid<512 own output (rowLocal, colF)
    const int rowLocal = tid >> 4;            // 0..31 for tid<512
    const int colF = tid & 15;
    const int m2f = rowLocal >> 4, tqf = (rowLocal >> 2) & 3, rf = rowLocal & 3;
    const int lf  = tqf * 16 + colF;
    float hold = 0.f;
    f32x4 accX = {0.f, 0.f, 0.f, 0.f};        // layer-0 x-part prefetch

    for (int i = 0; i <= TSTEPS; ++i) {
        const int t = layer ? (i - 1) : i;
        const bool valid = layer ? (t >= 0) : (t < TSTEPS);
        if (valid) {
            f32x4 accA = {0.f, 0.f, 0.f, 0.f};
            f32x4 accB = {0.f, 0.f, 0.f, 0.f};
            if (layer == 0) {
                if (kh < 4) {
                    if (i == 0) {
                        const float* xs = x + (size_t)t * (BATCH * IDIM) + arow * IDIM + kh * 32 + tq * 8;
                        ks_r2(*(const f32x4*)xs, *(const f32x4*)(xs + 4), wxh, wxl, accA);
                    } else {
                        accA = accX;   // prefetched under the previous barrier
                    }
                }
                if (t >= 1) {   // h0[t-1] = e0[t-1], 4 chunks (k = kh*128..)
                    const float* h0 = out + (size_t)(t - 1) * 131072 + arow * 2048
                                      + kh * 128 + tq * 8;
                    f32x4 bA[4], bB[4];
                    LD2(bA, h0, 0); LD2(bB, h0, 1);
                    PR2(bA, 0); PR2(bB, 1);
                }
            } else {
                // kh<4: e0[t] x Wi1 slice; kh>=4: h1[t-1] x Wh1 slice
                if ((kh < 4) || (t >= 1)) {
                    const int ts  = (kh < 4) ? t : (t - 1);
                    const float* src = out + (size_t)ts * 131072 + arow * 2048
                                       + ((kh < 4) ? 0 : 1024) + (kh & 3) * 256 + tq * 8;
                    f32x4 bA[4], bB[4];
                    LD2(bA, src, 0); LD2(bB, src, 1);
                    PR2(bA, 0); LD2(bA, src, 2);
                    PR2(bB, 1); LD2(bB, src, 3);
                    PR2(bA, 2); PR2(bB, 3);
                }
            }

            // cross-wave K-reduction (8 kh partials per m2 half)
            red[w * 64 + l] = accA + accB;
            __syncthreads();
            if (tid < 512) {   // 512 threads finalize one output each
                float s = 0.f;
                #pragma unroll
                for (int k8 = 0; k8 < 8; ++k8)
                    s += red[(k8 * 2 + m2f) * 64 + lf][rf];
                const float hnew = 0.5f * hold + 0.5f * tanhf(s);
                hold = hnew;
                const int row = mh * 32 + rowLocal;
                float* dst = out + (size_t)t * 131072 + row * 2048 + layer * 1024 + jbase + colF;
                __hip_atomic_store(dst, hnew, __ATOMIC_RELAXED, __HIP_MEMORY_SCOPE_AGENT);
            }
            __syncthreads();   // red reuse safety
        }
        if (i < TSTEPS) {
            barrier_arrive(cnt, (unsigned)(i + 1));
            // overlap: layer-0's x-part for step i+1 is barrier-independent
            if (layer == 0 && kh < 4 && (i + 1) < TSTEPS) {
                const float* xs = x + (size_t)(i + 1) * (BATCH * IDIM) + arow * IDIM + kh * 32 + tq * 8;
                f32x4 z = {0.f, 0.f, 0.f, 0.f};
                ks_r2(*(const f32x4*)xs, *(const f32x4*)(xs + 4), wxh, wxl, z);
                accX = z;
            }
            barrier_wait(cnt, (unsigned)(i + 1), layer);
        }
    }
}

extern "C" void kernel_launch(void* const* d_in, const int* in_sizes, int n_in,
                              void* d_out, int out_size, void* d_ws, size_t ws_size,
                              hipStream_t stream) {
    const float* x   = (const float*)d_in[0];
    const float* Wi0 = (const float*)d_in[1];
    const float* Wh0 = (const float*)d_in[2];
    const float* Wi1 = (const float*)d_in[3];
    const float* Wh1 = (const float*)d_in[4];
    float* out = (float*)d_out;
    unsigned short* wsU = (unsigned short*)d_ws;
    unsigned* cnt = (unsigned*)((char*)d_ws + CNT_OFF_BYTES);

    // arrival + both flag arrays must be 0 at kernel start on EVERY replay
    hipMemsetAsync((char*)d_ws + CNT_OFF_BYTES, 0, BAR_BYTES, stream);
    prep_kernel<<<256, 256, 0, stream>>>(Wi0, Wh0, Wi1, Wh1, wsU);

    void* args[] = {(void*)&x, (void*)&out, (void*)&wsU, (void*)&cnt};
    hipLaunchCooperativeKernel((const void*)reservoir_kernel,
                               dim3(NBLOCKS), dim3(NTHR), args, 0, stream);
}

// Round 16
// 4411.241 us; speedup vs baseline: 1.3925x; 1.3925x over previous
//
#include <hip/hip_runtime.h>
#include <math.h>

#define TSTEPS 512
#define BATCH  64
#define HDIM   1024
#define IDIM   128
#define NBLOCKS 256   // blocks 0..127: layer 0; 128..255: layer 1 (1 block/CU)
#define NTHR   512    // 8 waves: (m2 0..1) x (kh 0..3)

typedef __attribute__((ext_vector_type(8))) short bf16x8;
typedef __attribute__((ext_vector_type(4))) float f32x4;
typedef __attribute__((ext_vector_type(4))) unsigned u32x4;

// ---- ws: bf16 hi/lo weight planes (ushort units), then barrier area ----
#define WI0HI 0
#define WI0LO (WI0HI + 1024*128)
#define WH0HI (WI0LO + 1024*128)
#define WH0LO (WH0HI + 1024*1024)
#define WI1HI (WH0LO + 1024*1024)
#define WI1LO (WI1HI + 1024*1024)
#define WH1HI (WI1LO + 1024*1024)
#define WH1LO (WH1HI + 1024*1024)
#define WS_USHORTS (WH1LO + 1024*1024)
#define CNT_OFF_BYTES ((size_t)WS_USHORTS * 2)
// barrier area: 256 arrival lines (64B apart), indexed (dom*64 + jt).
// dom = layer*2 + mh. Four independent 64-block domains (batch halves
// never mix: row b of pre depends only on row b of h).
#define BAR_BYTES (256 * 64)   // 16 KB

__device__ __forceinline__ unsigned short bf_hi(float f) {
    unsigned u = __builtin_bit_cast(unsigned, f);
    unsigned r = u + 0x7fffu + ((u >> 16) & 1u);
    return (unsigned short)(r >> 16);
}
__device__ __forceinline__ float bf_tof(unsigned short h) {
    unsigned u = ((unsigned)h) << 16;
    return __builtin_bit_cast(float, u);
}

// fp32x8 (two f32x4 VALUES) -> bf16 hi + lo fragments via v_cvt_pk_bf16_f32
__device__ __forceinline__ void split8v(f32x4 a, f32x4 b,
                                        bf16x8& ah, bf16x8& al) {
    float fv[8] = {a[0], a[1], a[2], a[3], b[0], b[1], b[2], b[3]};
    u32x4 H, L;
    #pragma unroll
    for (int q = 0; q < 4; ++q) {
        const float f0 = fv[2 * q], f1 = fv[2 * q + 1];
        unsigned h;
        asm("v_cvt_pk_bf16_f32 %0, %1, %2" : "=v"(h) : "v"(f0), "v"(f1));
        const float h0 = __builtin_bit_cast(float, h << 16);
        const float h1 = __builtin_bit_cast(float, h & 0xffff0000u);
        unsigned lo;
        asm("v_cvt_pk_bf16_f32 %0, %1, %2" : "=v"(lo) : "v"(f0 - h0), "v"(f1 - h1));
        H[q] = h; L[q] = lo;
    }
    ah = __builtin_bit_cast(bf16x8, H);
    al = __builtin_bit_cast(bf16x8, L);
}

// one 32-k chunk from PRELOADED values: split + 3 MFMA (round-8..13 numerics)
__device__ __forceinline__ void ks_r2(f32x4 a, f32x4 b,
                                      bf16x8 bh, bf16x8 bl, f32x4& acc) {
    bf16x8 ah, al;
    split8v(a, b, ah, al);
    acc = __builtin_amdgcn_mfma_f32_16x16x32_bf16(ah, bh, acc, 0, 0, 0);
    acc = __builtin_amdgcn_mfma_f32_16x16x32_bf16(al, bh, acc, 0, 0, 0);
    acc = __builtin_amdgcn_mfma_f32_16x16x32_bf16(ah, bl, acc, 0, 0, 0);
}

// load 2 chunks (4 x dwordx4) of group g into a named buffer (static idx)
#define LD2(B, base, g) _Pragma("unroll") for (int c = 0; c < 2; ++c) { \
    (B)[2*c]   = *(const f32x4*)((base) + ((g)*2 + c) * 32); \
    (B)[2*c+1] = *(const f32x4*)((base) + ((g)*2 + c) * 32 + 4); }
// process 2 chunks of group g against weight frags wfh/wfl[wOff + g*2 + c]
#define PR2(B, wOff, g) _Pragma("unroll") for (int c = 0; c < 2; ++c) { \
    ks_r2((B)[2*c], (B)[2*c+1], wfh[(wOff)+(g)*2+c], wfl[(wOff)+(g)*2+c], \
          ((((g)*2+c) & 1) ? accA : accB)); }

// split fp32 weights into bf16 hi/lo planes in ws ([j][k] row-major)
__global__ void prep_kernel(const float* __restrict__ Wi0, const float* __restrict__ Wh0,
                            const float* __restrict__ Wi1, const float* __restrict__ Wh1,
                            unsigned short* __restrict__ wsU)
{
    const int n = 1024*128 + 3*1024*1024;
    for (int e = blockIdx.x * blockDim.x + threadIdx.x; e < n;
         e += gridDim.x * blockDim.x) {
        const float* src; int idx, hiOff, loOff;
        if (e < 1024*128)            { src = Wi0; idx = e;              hiOff = WI0HI; loOff = WI0LO; }
        else if (e < 1024*128 + 1024*1024)   { src = Wh0; idx = e - 1024*128;   hiOff = WH0HI; loOff = WH0LO; }
        else if (e < 1024*128 + 2*1024*1024) { src = Wi1; idx = e - 1024*128 - 1024*1024; hiOff = WI1HI; loOff = WI1LO; }
        else                         { src = Wh1; idx = e - 1024*128 - 2*1024*1024; hiOff = WH1HI; loOff = WH1LO; }
        float f = src[idx];
        unsigned short h = bf_hi(f);
        wsU[hiOff + idx] = h;
        wsU[loOff + idx] = bf_hi(f - bf_tof(h));
    }
}

// --- Single-hop ballot barrier over (layer, batch-half) domains ---
// arrive: block stores epoch to its OWN line (dom*64 + jt). No aggregator,
// no publish hop. wait: wave 0 polls the domain's 64 lines directly (one
// line per lane, ballot); L1 lanes also check the same-half L0 domain
// (e0[t] producers). Ordering chain unchanged from rounds 6-13: sc1 data
// stores drained by arrive-side __syncthreads; epochs monotonic.
__device__ __forceinline__ void barrier_arrive(unsigned* cnt, unsigned epoch,
                                               int dom, int jt) {
    __syncthreads();   // drain all waves' sc1 data stores (vmcnt 0)
    if (threadIdx.x == 0)
        __hip_atomic_store(cnt + (unsigned)(dom * 64 + jt) * 16, epoch,
                           __ATOMIC_RELAXED, __HIP_MEMORY_SCOPE_AGENT);
}
__device__ __forceinline__ void barrier_wait(unsigned* cnt, unsigned epoch,
                                             int layer, int mh) {
    const int tid = (int)threadIdx.x;
    if (tid < 64) {
        const int dom = layer * 2 + mh;
        unsigned* own = cnt + (unsigned)(dom * 64 + tid) * 16;
        if (layer == 0) {
            for (;;) {
                unsigned v = __hip_atomic_load(own, __ATOMIC_RELAXED,
                                               __HIP_MEMORY_SCOPE_AGENT);
                if (__ballot(v >= epoch) == ~0ull) break;
                __builtin_amdgcn_s_sleep(1);
            }
        } else {
            unsigned* up = cnt + (unsigned)(mh * 64 + tid) * 16;  // L0 same-half
            for (;;) {
                unsigned a = __hip_atomic_load(own, __ATOMIC_RELAXED,
                                               __HIP_MEMORY_SCOPE_AGENT);
                unsigned b = __hip_atomic_load(up, __ATOMIC_RELAXED,
                                               __HIP_MEMORY_SCOPE_AGENT);
                if (__ballot((a >= epoch) & (b >= epoch)) == ~0ull) break;
                __builtin_amdgcn_s_sleep(1);
            }
        }
    }
    __syncthreads();
}

// Persistent layer-decoupled kernel (round-13 champion structure). out[] IS
// the state trajectory; sc1 write-through stores, normal-cached first-touch
// reads (round-8 proven). Weights in registers; block = 32 batch-rows x 16 j.
__global__ __launch_bounds__(NTHR, 2) void reservoir_kernel(
    const float* __restrict__ x, float* __restrict__ out,
    const unsigned short* __restrict__ wsU, unsigned* __restrict__ cnt)
{
    __shared__ f32x4 red[8 * 64];   // 8 KB

    const int bid = blockIdx.x;
    const int layer = bid >> 7;
    const int rr  = bid & 127;
    const int jt  = rr >> 1, mh = rr & 1;
    const int dom = layer * 2 + mh;
    const int tid = (int)threadIdx.x;
    const int w   = __builtin_amdgcn_readfirstlane(tid >> 6);
    const int m2  = w & 1, kh = w >> 1;
    const int l   = tid & 63, lr = l & 15, tq = l >> 4;
    const int jbase = jt * 16;
    const int arow  = mh * 32 + m2 * 16 + lr;   // this lane's A row (batch)

    // ---- load this wave's weight fragments into registers (once) ----
    bf16x8 wfh[16], wfl[16];
    if (layer == 0) {
        const size_t rx = (size_t)(jbase + lr) * IDIM + kh * 32 + tq * 8;
        wfh[0] = *(const bf16x8*)(wsU + WI0HI + rx);
        wfl[0] = *(const bf16x8*)(wsU + WI0LO + rx);
        const size_t rh = (size_t)(jbase + lr) * HDIM + kh * 256 + tq * 8;
        #pragma unroll
        for (int ks = 0; ks < 8; ++ks) {
            wfh[1 + ks] = *(const bf16x8*)(wsU + WH0HI + rh + ks * 32);
            wfl[1 + ks] = *(const bf16x8*)(wsU + WH0LO + rh + ks * 32);
        }
    } else {
        const int hiOff = (kh < 2) ? WI1HI : WH1HI;
        const int loOff = (kh < 2) ? WI1LO : WH1LO;
        const size_t ro = (size_t)(jbase + lr) * HDIM + (kh & 1) * 512 + tq * 8;
        #pragma unroll
        for (int ks = 0; ks < 16; ++ks) {
            wfh[ks] = *(const bf16x8*)(wsU + hiOff + ro + ks * 32);
            wfl[ks] = *(const bf16x8*)(wsU + loOff + ro + ks * 32);
        }
    }

    // all-thread finalize: this thread owns output (rowLocal, colF)
    const int rowLocal = tid >> 4;            // 0..31
    const int colF = tid & 15;
    const int m2f = rowLocal >> 4, tqf = (rowLocal >> 2) & 3, rf = rowLocal & 3;
    const int lf  = tqf * 16 + colF;
    float hold = 0.f;
    f32x4 accX = {0.f, 0.f, 0.f, 0.f};        // layer-0 x-part prefetch

    for (int i = 0; i <= TSTEPS; ++i) {
        const int t = layer ? (i - 1) : i;
        const bool valid = layer ? (t >= 0) : (t < TSTEPS);
        if (valid) {
            f32x4 accA = {0.f, 0.f, 0.f, 0.f};
            f32x4 accB = {0.f, 0.f, 0.f, 0.f};
            if (layer == 0) {
                if (i == 0) {
                    f32x4 xa = *(const f32x4*)(x + (size_t)t * (BATCH * IDIM) + arow * IDIM + kh * 32 + tq * 8);
                    f32x4 xb = *(const f32x4*)(x + (size_t)t * (BATCH * IDIM) + arow * IDIM + kh * 32 + tq * 8 + 4);
                    ks_r2(xa, xb, wfh[0], wfl[0], accA);
                } else {
                    accA = accX;   // prefetched under the previous barrier
                }
                if (t >= 1) {   // h0[t-1] = e0[t-1] = out[t-1][.][0][.]
                    const float* h0 = out + (size_t)(t - 1) * 131072 + arow * 2048
                                      + kh * 256 + tq * 8;
                    f32x4 bA[4], bB[4];
                    LD2(bA, h0, 0); LD2(bB, h0, 1);
                    PR2(bA, 1, 0); LD2(bA, h0, 2);
                    PR2(bB, 1, 1); LD2(bB, h0, 3);
                    PR2(bA, 1, 2); PR2(bB, 1, 3);
                }
            } else {
                // kh<2: e0[t] x Wi1 slice; kh>=2: h1[t-1] x Wh1 slice
                if ((kh < 2) || (t >= 1)) {
                    const int ts  = (kh < 2) ? t : (t - 1);
                    const float* src = out + (size_t)ts * 131072 + arow * 2048
                                       + ((kh < 2) ? 0 : 1024) + (kh & 1) * 512 + tq * 8;
                    f32x4 bA[4], bB[4];
                    LD2(bA, src, 0); LD2(bB, src, 1);
                    PR2(bA, 0, 0); LD2(bA, src, 2);
                    PR2(bB, 0, 1); LD2(bB, src, 3);
                    PR2(bA, 0, 2); LD2(bA, src, 4);
                    PR2(bB, 0, 3); LD2(bB, src, 5);
                    PR2(bA, 0, 4); LD2(bA, src, 6);
                    PR2(bB, 0, 5); LD2(bB, src, 7);
                    PR2(bA, 0, 6); PR2(bB, 0, 7);
                }
            }

            // cross-wave K-reduction (4 kh partials per m2)
            red[w * 64 + l] = accA + accB;
            __syncthreads();
            {   // all 512 threads finalize one output each
                float s = 0.f;
                #pragma unroll
                for (int k4 = 0; k4 < 4; ++k4)
                    s += red[(k4 * 2 + m2f) * 64 + lf][rf];
                const float hnew = 0.5f * hold + 0.5f * tanhf(s);
                hold = hnew;
                const int row = mh * 32 + rowLocal;
                float* dst = out + (size_t)t * 131072 + row * 2048 + layer * 1024 + jbase + colF;
                __hip_atomic_store(dst, hnew, __ATOMIC_RELAXED, __HIP_MEMORY_SCOPE_AGENT);
            }
            __syncthreads();   // red reuse safety
        }
        if (i < TSTEPS) {
            barrier_arrive(cnt, (unsigned)(i + 1), dom, jt);
            // overlap: layer-0's x-part for step i+1 is barrier-independent
            if (layer == 0 && (i + 1) < TSTEPS) {
                const float* xs = x + (size_t)(i + 1) * (BATCH * IDIM) + arow * IDIM + kh * 32 + tq * 8;
                f32x4 xa = *(const f32x4*)(xs);
                f32x4 xb = *(const f32x4*)(xs + 4);
                f32x4 z = {0.f, 0.f, 0.f, 0.f};
                ks_r2(xa, xb, wfh[0], wfl[0], z);
                accX = z;
            }
            barrier_wait(cnt, (unsigned)(i + 1), layer, mh);
        }
    }
}

extern "C" void kernel_launch(void* const* d_in, const int* in_sizes, int n_in,
                              void* d_out, int out_size, void* d_ws, size_t ws_size,
                              hipStream_t stream) {
    const float* x   = (const float*)d_in[0];
    const float* Wi0 = (const float*)d_in[1];
    const float* Wh0 = (const float*)d_in[2];
    const float* Wi1 = (const float*)d_in[3];
    const float* Wh1 = (const float*)d_in[4];
    float* out = (float*)d_out;
    unsigned short* wsU = (unsigned short*)d_ws;
    unsigned* cnt = (unsigned*)((char*)d_ws + CNT_OFF_BYTES);

    // arrival lines must be 0 at kernel start on EVERY replay
    hipMemsetAsync((char*)d_ws + CNT_OFF_BYTES, 0, BAR_BYTES, stream);
    prep_kernel<<<256, 256, 0, stream>>>(Wi0, Wh0, Wi1, Wh1, wsU);

    void* args[] = {(void*)&x, (void*)&out, (void*)&wsU, (void*)&cnt};
    hipLaunchCooperativeKernel((const void*)reservoir_kernel,
                               dim3(NBLOCKS), dim3(NTHR), args, 0, stream);
}

// Round 17
// 4208.467 us; speedup vs baseline: 1.4596x; 1.0482x over previous
//
#include <hip/hip_runtime.h>
#include <math.h>

#define TSTEPS 512
#define BATCH  64
#define HDIM   1024
#define IDIM   128
#define NBLOCKS 256   // blocks 0..127: layer 0; 128..255: layer 1 (1 block/CU)
#define NTHR   512    // 8 waves: (m2 0..1) x (kh 0..3)

typedef __attribute__((ext_vector_type(8))) short bf16x8;
typedef __attribute__((ext_vector_type(4))) float f32x4;
typedef __attribute__((ext_vector_type(4))) unsigned u32x4;

// ---- ws: bf16 hi/lo weight planes (ushort units), then barrier area ----
#define WI0HI 0
#define WI0LO (WI0HI + 1024*128)
#define WH0HI (WI0LO + 1024*128)
#define WH0LO (WH0HI + 1024*1024)
#define WI1HI (WH0LO + 1024*1024)
#define WI1LO (WI1HI + 1024*1024)
#define WH1HI (WI1LO + 1024*1024)
#define WH1LO (WH1HI + 1024*1024)
#define WS_USHORTS (WH1LO + 1024*1024)
#define CNT_OFF_BYTES ((size_t)WS_USHORTS * 2)
// barrier area: 256 arrival lines (64B apart), indexed (dom*64 + jt),
// dom = layer*2 + mh. Arrival value = completed-iteration + 1 (monotonic).
#define BAR_BYTES (256 * 64)   // 16 KB

__device__ __forceinline__ unsigned short bf_hi(float f) {
    unsigned u = __builtin_bit_cast(unsigned, f);
    unsigned r = u + 0x7fffu + ((u >> 16) & 1u);
    return (unsigned short)(r >> 16);
}
__device__ __forceinline__ float bf_tof(unsigned short h) {
    unsigned u = ((unsigned)h) << 16;
    return __builtin_bit_cast(float, u);
}

// fp32x8 (two f32x4 VALUES) -> bf16 hi + lo fragments via v_cvt_pk_bf16_f32
__device__ __forceinline__ void split8v(f32x4 a, f32x4 b,
                                        bf16x8& ah, bf16x8& al) {
    float fv[8] = {a[0], a[1], a[2], a[3], b[0], b[1], b[2], b[3]};
    u32x4 H, L;
    #pragma unroll
    for (int q = 0; q < 4; ++q) {
        const float f0 = fv[2 * q], f1 = fv[2 * q + 1];
        unsigned h;
        asm("v_cvt_pk_bf16_f32 %0, %1, %2" : "=v"(h) : "v"(f0), "v"(f1));
        const float h0 = __builtin_bit_cast(float, h << 16);
        const float h1 = __builtin_bit_cast(float, h & 0xffff0000u);
        unsigned lo;
        asm("v_cvt_pk_bf16_f32 %0, %1, %2" : "=v"(lo) : "v"(f0 - h0), "v"(f1 - h1));
        H[q] = h; L[q] = lo;
    }
    ah = __builtin_bit_cast(bf16x8, H);
    al = __builtin_bit_cast(bf16x8, L);
}

// one 32-k chunk from PRELOADED values: split + 3 MFMA (round-8..16 numerics)
__device__ __forceinline__ void ks_r2(f32x4 a, f32x4 b,
                                      bf16x8 bh, bf16x8 bl, f32x4& acc) {
    bf16x8 ah, al;
    split8v(a, b, ah, al);
    acc = __builtin_amdgcn_mfma_f32_16x16x32_bf16(ah, bh, acc, 0, 0, 0);
    acc = __builtin_amdgcn_mfma_f32_16x16x32_bf16(al, bh, acc, 0, 0, 0);
    acc = __builtin_amdgcn_mfma_f32_16x16x32_bf16(ah, bl, acc, 0, 0, 0);
}

// load 2 chunks (4 x dwordx4) of group g into a named buffer (static idx)
#define LD2(B, base, g) _Pragma("unroll") for (int c = 0; c < 2; ++c) { \
    (B)[2*c]   = *(const f32x4*)((base) + ((g)*2 + c) * 32); \
    (B)[2*c+1] = *(const f32x4*)((base) + ((g)*2 + c) * 32 + 4); }
// process 2 chunks of group g against weight frags wfh/wfl[wOff + g*2 + c]
#define PR2(B, wOff, g) _Pragma("unroll") for (int c = 0; c < 2; ++c) { \
    ks_r2((B)[2*c], (B)[2*c+1], wfh[(wOff)+(g)*2+c], wfl[(wOff)+(g)*2+c], \
          ((((g)*2+c) & 1) ? accA : accB)); }

// split fp32 weights into bf16 hi/lo planes in ws ([j][k] row-major)
__global__ void prep_kernel(const float* __restrict__ Wi0, const float* __restrict__ Wh0,
                            const float* __restrict__ Wi1, const float* __restrict__ Wh1,
                            unsigned short* __restrict__ wsU)
{
    const int n = 1024*128 + 3*1024*1024;
    for (int e = blockIdx.x * blockDim.x + threadIdx.x; e < n;
         e += gridDim.x * blockDim.x) {
        const float* src; int idx, hiOff, loOff;
        if (e < 1024*128)            { src = Wi0; idx = e;              hiOff = WI0HI; loOff = WI0LO; }
        else if (e < 1024*128 + 1024*1024)   { src = Wh0; idx = e - 1024*128;   hiOff = WH0HI; loOff = WH0LO; }
        else if (e < 1024*128 + 2*1024*1024) { src = Wi1; idx = e - 1024*128 - 1024*1024; hiOff = WI1HI; loOff = WI1LO; }
        else                         { src = Wh1; idx = e - 1024*128 - 2*1024*1024; hiOff = WH1HI; loOff = WH1LO; }
        float f = src[idx];
        unsigned short h = bf_hi(f);
        wsU[hiOff + idx] = h;
        wsU[loOff + idx] = bf_hi(f - bf_tof(h));
    }
}

// --- Per-wave dataflow wait ---
// out[] is write-once, so the ONLY ordering needed is read-after-write:
// each wave waits for exactly the producer blocks of its k-range (k-index of
// state = j-index of producer). Lanes poll (lane & mask) lines; ballot.
// Arrival value v means the block completed iteration v-1 (data for its
// output step is MALL-visible: sc1 stores drained before the flag store).
__device__ __forceinline__ void wave_wait(unsigned* cnt, unsigned epoch,
                                          int baseLine, int mask) {
    const int lane = (int)(threadIdx.x & 63);
    unsigned* p = cnt + (unsigned)(baseLine + (lane & mask)) * 16;
    for (;;) {
        unsigned v = __hip_atomic_load(p, __ATOMIC_RELAXED, __HIP_MEMORY_SCOPE_AGENT);
        if (__ballot(v >= epoch) == ~0ull) break;
        __builtin_amdgcn_s_sleep(1);
    }
}

// Persistent dataflow kernel (round-16 data path, block barrier removed).
// out[] IS the state trajectory; sc1 write-through stores, normal-cached
// first-touch reads (round-8 proven). Weights in registers.
__global__ __launch_bounds__(NTHR, 2) void reservoir_kernel(
    const float* __restrict__ x, float* __restrict__ out,
    const unsigned short* __restrict__ wsU, unsigned* __restrict__ cnt)
{
    __shared__ f32x4 red[8 * 64];   // 8 KB

    const int bid = blockIdx.x;
    const int layer = bid >> 7;
    const int rr  = bid & 127;
    const int jt  = rr >> 1, mh = rr & 1;
    const int dom = layer * 2 + mh;
    const int tid = (int)threadIdx.x;
    const int w   = __builtin_amdgcn_readfirstlane(tid >> 6);
    const int m2  = w & 1, kh = w >> 1;
    const int l   = tid & 63, lr = l & 15, tq = l >> 4;
    const int jbase = jt * 16;
    const int arow  = mh * 32 + m2 * 16 + lr;   // this lane's A row (batch)

    // ---- load this wave's weight fragments into registers (once) ----
    bf16x8 wfh[16], wfl[16];
    if (layer == 0) {
        const size_t rx = (size_t)(jbase + lr) * IDIM + kh * 32 + tq * 8;
        wfh[0] = *(const bf16x8*)(wsU + WI0HI + rx);
        wfl[0] = *(const bf16x8*)(wsU + WI0LO + rx);
        const size_t rh = (size_t)(jbase + lr) * HDIM + kh * 256 + tq * 8;
        #pragma unroll
        for (int ks = 0; ks < 8; ++ks) {
            wfh[1 + ks] = *(const bf16x8*)(wsU + WH0HI + rh + ks * 32);
            wfl[1 + ks] = *(const bf16x8*)(wsU + WH0LO + rh + ks * 32);
        }
    } else {
        const int hiOff = (kh < 2) ? WI1HI : WH1HI;
        const int loOff = (kh < 2) ? WI1LO : WH1LO;
        const size_t ro = (size_t)(jbase + lr) * HDIM + (kh & 1) * 512 + tq * 8;
        #pragma unroll
        for (int ks = 0; ks < 16; ++ks) {
            wfh[ks] = *(const bf16x8*)(wsU + hiOff + ro + ks * 32);
            wfl[ks] = *(const bf16x8*)(wsU + loOff + ro + ks * 32);
        }
    }

    // all-thread finalize: this thread owns output (rowLocal, colF)
    const int rowLocal = tid >> 4;            // 0..31
    const int colF = tid & 15;
    const int m2f = rowLocal >> 4, tqf = (rowLocal >> 2) & 3, rf = rowLocal & 3;
    const int lf  = tqf * 16 + colF;
    float hold = 0.f;

    for (int i = 0; i <= TSTEPS; ++i) {
        const int t = layer ? (i - 1) : i;
        const bool valid = layer ? (t >= 0) : (t < TSTEPS);
        if (valid) {
            f32x4 accA = {0.f, 0.f, 0.f, 0.f};
            f32x4 accB = {0.f, 0.f, 0.f, 0.f};
            if (layer == 0) {
                {   // x part first: no dependency, overlaps peers' waits
                    const float* xs = x + (size_t)t * (BATCH * IDIM) + arow * IDIM + kh * 32 + tq * 8;
                    ks_r2(*(const f32x4*)xs, *(const f32x4*)(xs + 4), wfh[0], wfl[0], accA);
                }
                if (t >= 1) {   // h0[t-1] k-range kh*256: producers dom(0,mh), jt = kh*16..+16
                    wave_wait(cnt, (unsigned)i, mh * 64 + kh * 16, 15);
                    const float* h0 = out + (size_t)(t - 1) * 131072 + arow * 2048
                                      + kh * 256 + tq * 8;
                    f32x4 bA[4], bB[4];
                    LD2(bA, h0, 0); LD2(bB, h0, 1);
                    PR2(bA, 1, 0); LD2(bA, h0, 2);
                    PR2(bB, 1, 1); LD2(bB, h0, 3);
                    PR2(bA, 1, 2); PR2(bB, 1, 3);
                }
            } else {
                // kh<2: e0[t] (producers dom(0,mh), jt=kh*32..+32);
                // kh>=2: h1[t-1] (producers dom(1,mh), jt=(kh-2)*32..+32)
                if ((kh < 2) || (t >= 1)) {
                    const int ts  = (kh < 2) ? t : (t - 1);
                    const int pbase = (kh < 2) ? (mh * 64 + kh * 32)
                                               : ((2 + mh) * 64 + (kh - 2) * 32);
                    wave_wait(cnt, (unsigned)i, pbase, 31);
                    const float* src = out + (size_t)ts * 131072 + arow * 2048
                                       + ((kh < 2) ? 0 : 1024) + (kh & 1) * 512 + tq * 8;
                    f32x4 bA[4], bB[4];
                    LD2(bA, src, 0); LD2(bB, src, 1);
                    PR2(bA, 0, 0); LD2(bA, src, 2);
                    PR2(bB, 0, 1); LD2(bB, src, 3);
                    PR2(bA, 0, 2); LD2(bA, src, 4);
                    PR2(bB, 0, 3); LD2(bB, src, 5);
                    PR2(bA, 0, 4); LD2(bA, src, 6);
                    PR2(bB, 0, 5); LD2(bB, src, 7);
                    PR2(bA, 0, 6); PR2(bB, 0, 7);
                }
            }

            // cross-wave K-reduction (4 kh partials per m2)
            red[w * 64 + l] = accA + accB;
            __syncthreads();
            {   // all 512 threads finalize one output each
                float s = 0.f;
                #pragma unroll
                for (int k4 = 0; k4 < 4; ++k4)
                    s += red[(k4 * 2 + m2f) * 64 + lf][rf];
                const float hnew = 0.5f * hold + 0.5f * tanhf(s);
                hold = hnew;
                const int row = mh * 32 + rowLocal;
                float* dst = out + (size_t)t * 131072 + row * 2048 + layer * 1024 + jbase + colF;
                __hip_atomic_store(dst, hnew, __ATOMIC_RELAXED, __HIP_MEMORY_SCOPE_AGENT);
            }
        }
        if (i < TSTEPS) {
            // red-reuse safety + drain of all waves' sc1 out-stores (vmcnt 0
            // before s_barrier), then publish this block's arrival.
            __syncthreads();
            if (tid == 0)
                __hip_atomic_store(cnt + (unsigned)(dom * 64 + jt) * 16,
                                   (unsigned)(i + 1),
                                   __ATOMIC_RELAXED, __HIP_MEMORY_SCOPE_AGENT);
        }
    }
}

extern "C" void kernel_launch(void* const* d_in, const int* in_sizes, int n_in,
                              void* d_out, int out_size, void* d_ws, size_t ws_size,
                              hipStream_t stream) {
    const float* x   = (const float*)d_in[0];
    const float* Wi0 = (const float*)d_in[1];
    const float* Wh0 = (const float*)d_in[2];
    const float* Wi1 = (const float*)d_in[3];
    const float* Wh1 = (const float*)d_in[4];
    float* out = (float*)d_out;
    unsigned short* wsU = (unsigned short*)d_ws;
    unsigned* cnt = (unsigned*)((char*)d_ws + CNT_OFF_BYTES);

    // arrival lines must be 0 at kernel start on EVERY replay
    hipMemsetAsync((char*)d_ws + CNT_OFF_BYTES, 0, BAR_BYTES, stream);
    prep_kernel<<<256, 256, 0, stream>>>(Wi0, Wh0, Wi1, Wh1, wsU);

    void* args[] = {(void*)&x, (void*)&out, (void*)&wsU, (void*)&cnt};
    hipLaunchCooperativeKernel((const void*)reservoir_kernel,
                               dim3(NBLOCKS), dim3(NTHR), args, 0, stream);
}